// Round 1
// baseline (527.012 us; speedup 1.0000x reference)
//
#include <hip/hip_runtime.h>
#include <hip/hip_bf16.h>

#define N_ROWS 16384   // B*T
#define K_CODES 4096
#define D_DIM 256

#define BM 128
#define BN 128
#define DK 32
#define LDST 132       // padded LDS leading dim (floats), multiple of 4 for b128 alignment
#define KSPLIT 8
#define CT_PER (K_CODES / KSPLIT / BN)   // 4 code-tiles per block

// ---------------- prep: ||e_k||^2, ||x_n||^2, key init, loss zero ----------------
__global__ __launch_bounds__(256) void vq_prep(const float* __restrict__ x,
                                               const float* __restrict__ e,
                                               float* __restrict__ en,
                                               float* __restrict__ xx,
                                               unsigned long long* __restrict__ keys,
                                               double* __restrict__ loss_acc) {
    int tid  = threadIdx.x;
    int w    = blockIdx.x * 4 + (tid >> 6);   // wave id, 20480 total
    int lane = tid & 63;
    const float* src;
    float* dst;
    if (w < K_CODES) { src = e + (size_t)w * D_DIM;            dst = en + w; }
    else             { src = x + (size_t)(w - K_CODES) * D_DIM; dst = xx + (w - K_CODES); }
    float4 v = reinterpret_cast<const float4*>(src)[lane];     // 64 lanes * 16B = 256 floats
    float s = v.x * v.x + v.y * v.y + v.z * v.z + v.w * v.w;
#pragma unroll
    for (int m = 32; m; m >>= 1) s += __shfl_xor(s, m, 64);
    if (lane == 0) *dst = s;

    int g = blockIdx.x * 256 + tid;
    if (g < N_ROWS) keys[g] = ~0ull;
    if (g == 0) *loss_acc = 0.0;
}

// ---------------- main: tiled score GEMM + running argmin ----------------
// dist'(n,k) = (||x_n||^2 + ||e_k||^2) - 2*dot(x_n, e_k)   (matches reference assoc.)
__global__ __launch_bounds__(256) void vq_argmin(const float* __restrict__ x,
                                                 const float* __restrict__ e,
                                                 const float* __restrict__ en,
                                                 const float* __restrict__ xx,
                                                 unsigned long long* __restrict__ keys) {
    __shared__ __align__(16) float smem[2 * DK * LDST];   // 8448 floats = 33 KB
    float* xs = smem;
    float* es = smem + DK * LDST;

    int tid = threadIdx.x;
    int rb  = blockIdx.x >> 3;          // 128 row blocks
    int ks  = blockIdx.x & 7;           // 8-way K split
    int r0  = rb * BM;
    int c00 = ks * (K_CODES / KSPLIT);  // 512 codes per split

    int tm = tid & 15;                  // row-group selector
    int tn = tid >> 4;                  // code-group selector

    float xxv[8];
#pragma unroll
    for (int ii = 0; ii < 8; ++ii)
        xxv[ii] = xx[r0 + (ii >> 2) * 64 + tm * 4 + (ii & 3)];

    float bestd[8];
    int   besti[8];
#pragma unroll
    for (int ii = 0; ii < 8; ++ii) { bestd[ii] = 3.4e38f; besti[ii] = 0; }

    for (int ct = 0; ct < CT_PER; ++ct) {
        int cbase = c00 + ct * BN;
        float acc[8][8];
#pragma unroll
        for (int ii = 0; ii < 8; ++ii)
#pragma unroll
            for (int jj = 0; jj < 8; ++jj) acc[ii][jj] = 0.f;

        for (int dk = 0; dk < D_DIM / DK; ++dk) {   // 8 chunks
            int d0 = dk * DK;
            __syncthreads();
            // stage x[128][32] and e[128][32] transposed into LDS
#pragma unroll
            for (int t = 0; t < 4; ++t) {
                int q  = tid + t * 256;          // 0..1023
                int r  = q >> 3;                 // 0..127
                int dq = (q & 7) << 2;           // 0,4,...,28
                float4 vx = *reinterpret_cast<const float4*>(&x[(size_t)(r0 + r) * D_DIM + d0 + dq]);
                float4 ve = *reinterpret_cast<const float4*>(&e[(size_t)(cbase + r) * D_DIM + d0 + dq]);
                xs[(dq + 0) * LDST + r] = vx.x;
                xs[(dq + 1) * LDST + r] = vx.y;
                xs[(dq + 2) * LDST + r] = vx.z;
                xs[(dq + 3) * LDST + r] = vx.w;
                es[(dq + 0) * LDST + r] = ve.x;
                es[(dq + 1) * LDST + r] = ve.y;
                es[(dq + 2) * LDST + r] = ve.z;
                es[(dq + 3) * LDST + r] = ve.w;
            }
            __syncthreads();
#pragma unroll 4
            for (int d = 0; d < DK; ++d) {
                float4 a0 = *reinterpret_cast<const float4*>(&xs[d * LDST + tm * 4]);
                float4 a1 = *reinterpret_cast<const float4*>(&xs[d * LDST + 64 + tm * 4]);
                float4 b0 = *reinterpret_cast<const float4*>(&es[d * LDST + tn * 4]);
                float4 b1 = *reinterpret_cast<const float4*>(&es[d * LDST + 64 + tn * 4]);
                float A[8] = {a0.x, a0.y, a0.z, a0.w, a1.x, a1.y, a1.z, a1.w};
                float B[8] = {b0.x, b0.y, b0.z, b0.w, b1.x, b1.y, b1.z, b1.w};
#pragma unroll
                for (int ii = 0; ii < 8; ++ii)
#pragma unroll
                    for (int jj = 0; jj < 8; ++jj) acc[ii][jj] += A[ii] * B[jj];
            }
        }
        // epilogue: distances + running argmin (codes ascending for tie->first)
#pragma unroll
        for (int jj = 0; jj < 8; ++jj) {
            int c = cbase + (jj >> 2) * 64 + tn * 4 + (jj & 3);
            float env = en[c];
#pragma unroll
            for (int ii = 0; ii < 8; ++ii) {
                float dist = (xxv[ii] + env) - 2.0f * acc[ii][jj];
                if (dist < bestd[ii]) { bestd[ii] = dist; besti[ii] = c; }
            }
        }
    }

    // cross-thread (tn) reduction per row via LDS, then packed atomicMin merge
    __syncthreads();
    float* sd = smem;                       // 2048 floats
    int*   si = (int*)(smem + 2048);        // 2048 ints
#pragma unroll
    for (int ii = 0; ii < 8; ++ii) {
        int row = (ii >> 2) * 64 + tm * 4 + (ii & 3);
        sd[row * 16 + tn] = bestd[ii];
        si[row * 16 + tn] = besti[ii];
    }
    __syncthreads();
    if (tid < BM) {
        int row = tid;
        float bb = sd[row * 16];
        int   bj = si[row * 16];
#pragma unroll
        for (int t = 1; t < 16; ++t) {
            float dd = sd[row * 16 + t];
            int   cc = si[row * 16 + t];
            if (dd < bb || (dd == bb && cc < bj)) { bb = dd; bj = cc; }
        }
        unsigned int ub = __float_as_uint(bb);
        ub ^= (ub & 0x80000000u) ? 0xFFFFFFFFu : 0x80000000u;   // order-preserving map
        unsigned long long key = ((unsigned long long)ub << 32) | (unsigned int)bj;
        atomicMin(&keys[r0 + row], key);
    }
}

// ---------------- gather + straight-through out + loss ----------------
__global__ __launch_bounds__(256) void vq_out(const float* __restrict__ x,
                                              const float* __restrict__ e,
                                              const unsigned long long* __restrict__ keys,
                                              float* __restrict__ out,
                                              double* __restrict__ loss_acc) {
    int gtid = blockIdx.x * 256 + threadIdx.x;
    float ls = 0.f;
    for (int i = gtid; i < N_ROWS * D_DIM; i += 256 * 256) {
        int n = i >> 8, d = i & 255;
        int idx = (int)(unsigned int)(keys[n] & 0xffffffffull);
        float xv = x[i];
        float v  = e[(size_t)idx * D_DIM + d];
        out[i] = xv + (v - xv);             // matches x + sg(values - x) rounding
        float s = xv - v;
        ls += s * s;
    }
    if (gtid < N_ROWS)
        out[(size_t)N_ROWS * D_DIM + gtid] = (float)(unsigned int)(keys[gtid] & 0xffffffffull);

#pragma unroll
    for (int m = 32; m; m >>= 1) ls += __shfl_xor(ls, m, 64);
    __shared__ float lred[4];
    if ((threadIdx.x & 63) == 0) lred[threadIdx.x >> 6] = ls;
    __syncthreads();
    if (threadIdx.x == 0) {
        double tot = (double)lred[0] + (double)lred[1] + (double)lred[2] + (double)lred[3];
        atomicAdd(loss_acc, tot);
    }
}

__global__ void vq_final(const double* __restrict__ loss_acc, float* __restrict__ out) {
    float L = (float)(*loss_acc / (double)((size_t)N_ROWS * D_DIM));
    out[(size_t)N_ROWS * D_DIM + N_ROWS] = L + 0.2f * L;   // loss1 + BETA*loss2
}

extern "C" void kernel_launch(void* const* d_in, const int* in_sizes, int n_in,
                              void* d_out, int out_size, void* d_ws, size_t ws_size,
                              hipStream_t stream) {
    const float* x = (const float*)d_in[0];
    const float* e = (const float*)d_in[1];
    float* out = (float*)d_out;
    char* ws = (char*)d_ws;
    // ws layout: [0,8) double loss | [64,16448) en[4096] | [16448,81984) xx[16384]
    //            [81984,213056) keys[16384] (u64)
    double* loss_acc = (double*)ws;
    float* en = (float*)(ws + 64);
    float* xx = (float*)(ws + 64 + K_CODES * 4);
    unsigned long long* keys = (unsigned long long*)(ws + 64 + K_CODES * 4 + N_ROWS * 4);

    vq_prep<<<5120, 256, 0, stream>>>(x, e, en, xx, keys, loss_acc);
    vq_argmin<<<(N_ROWS / BM) * KSPLIT, 256, 0, stream>>>(x, e, en, xx, keys);
    vq_out<<<256, 256, 0, stream>>>(x, e, keys, out, loss_acc);
    vq_final<<<1, 1, 0, stream>>>(loss_acc, out);
}

// Round 4
// 301.831 us; speedup vs baseline: 1.7460x; 1.7460x over previous
//
#include <hip/hip_runtime.h>
#include <hip/hip_bf16.h>

#define N_ROWS 16384   // B*T
#define K_CODES 4096
#define D_DIM 256
#define LDST 40        // LDS row stride in bf16 units (32 + 8 pad)

typedef short short8 __attribute__((ext_vector_type(8)));
typedef float floatx4 __attribute__((ext_vector_type(4)));

// ---------------- prep: ||e||^2, ||x||^2, loss zero ----------------
__global__ __launch_bounds__(256) void vq_prep(const float* __restrict__ x,
                                               const float* __restrict__ e,
                                               float* __restrict__ en,
                                               float* __restrict__ xx,
                                               double* __restrict__ loss_acc) {
    int tid  = threadIdx.x;
    int w    = blockIdx.x * 4 + (tid >> 6);   // 20480 waves
    int lane = tid & 63;
    const float* src;
    float* dst;
    if (w < K_CODES) { src = e + (size_t)w * D_DIM;             dst = en + w; }
    else             { src = x + (size_t)(w - K_CODES) * D_DIM; dst = xx + (w - K_CODES); }
    float4 v = reinterpret_cast<const float4*>(src)[lane];
    float s = v.x * v.x + v.y * v.y + v.z * v.z + v.w * v.w;
#pragma unroll
    for (int m = 32; m; m >>= 1) s += __shfl_xor(s, m, 64);
    if (lane == 0) *dst = s;
    if (blockIdx.x == 0 && tid == 0) *loss_acc = 0.0;
}

// split 8 fp32 -> 8 bf16 hi (trunc) + 8 bf16 lo (trunc of x - hi)
__device__ inline void cvt8(const float4 p, const float4 q, uint4* h, uint4* l) {
    float f[8] = {p.x, p.y, p.z, p.w, q.x, q.y, q.z, q.w};
    unsigned int hh[8], ll[8];
#pragma unroll
    for (int i = 0; i < 8; ++i) {
        unsigned int u  = __float_as_uint(f[i]);
        unsigned int ht = u & 0xFFFF0000u;                 // trunc-to-bf16 as f32 bits
        float lo = f[i] - __uint_as_float(ht);             // exact
        hh[i] = u >> 16;
        ll[i] = __float_as_uint(lo) >> 16;
    }
    *h = make_uint4(hh[0] | (hh[1] << 16), hh[2] | (hh[3] << 16),
                    hh[4] | (hh[5] << 16), hh[6] | (hh[7] << 16));
    *l = make_uint4(ll[0] | (ll[1] << 16), ll[2] | (ll[3] << 16),
                    ll[4] | (ll[5] << 16), ll[6] | (ll[7] << 16));
}

// ------- main: bf16 split 3-pass MFMA GEMM + per-(row,cbk,wn) top-2 -------
__global__ __launch_bounds__(256) void vq_argmin(const float* __restrict__ x,
                                                 const float* __restrict__ e,
                                                 const float* __restrict__ en,
                                                 const float* __restrict__ xx,
                                                 unsigned long long* __restrict__ top2) {
    __shared__ __align__(16) unsigned short sm[4 * 128 * LDST];   // 40 KB
    unsigned short* xh = sm;
    unsigned short* xl = sm + 128 * LDST;
    unsigned short* eh = sm + 2 * 128 * LDST;
    unsigned short* el = sm + 3 * 128 * LDST;

    int tid  = threadIdx.x;
    int cbk  = blockIdx.x & 31;
    int rb   = blockIdx.x >> 5;
    int r0   = rb * 128, c0 = cbk * 128;
    int lane = tid & 63;
    int wave = tid >> 6;
    int wm   = wave >> 1, wn = wave & 1;   // 2x2 wave grid, 64x64 per wave
    int l15  = lane & 15, lq = lane >> 4;

    floatx4 acc[4][4];
#pragma unroll
    for (int mt = 0; mt < 4; ++mt)
#pragma unroll
        for (int nt = 0; nt < 4; ++nt) acc[mt][nt] = (floatx4)0.f;

    // staging assignment: thread -> (row tr, half th of the 32-wide chunk)
    int tr = tid >> 1, th = tid & 1;
    const float* xrow = x + (size_t)(r0 + tr) * D_DIM + th * 16;
    const float* erow = e + (size_t)(c0 + tr) * D_DIM + th * 16;
    int wb = tr * LDST + th * 16;

    int raddrA = (wm * 64 + l15) * LDST;   // + mt*16*LDST
    int raddrB = (wn * 64 + l15) * LDST;
    int ko     = lq * 8;

    for (int ch = 0; ch < 8; ++ch) {       // 8 chunks of 32 dims
        int d0 = ch * 32;
        __syncthreads();
        float4 vx0 = *(const float4*)(xrow + d0);
        float4 vx1 = *(const float4*)(xrow + d0 + 4);
        float4 vx2 = *(const float4*)(xrow + d0 + 8);
        float4 vx3 = *(const float4*)(xrow + d0 + 12);
        float4 ve0 = *(const float4*)(erow + d0);
        float4 ve1 = *(const float4*)(erow + d0 + 4);
        float4 ve2 = *(const float4*)(erow + d0 + 8);
        float4 ve3 = *(const float4*)(erow + d0 + 12);
        uint4 h, l;
        cvt8(vx0, vx1, &h, &l);
        *(uint4*)&xh[wb]     = h;  *(uint4*)&xl[wb]     = l;
        cvt8(vx2, vx3, &h, &l);
        *(uint4*)&xh[wb + 8] = h;  *(uint4*)&xl[wb + 8] = l;
        cvt8(ve0, ve1, &h, &l);
        *(uint4*)&eh[wb]     = h;  *(uint4*)&el[wb]     = l;
        cvt8(ve2, ve3, &h, &l);
        *(uint4*)&eh[wb + 8] = h;  *(uint4*)&el[wb + 8] = l;
        __syncthreads();

        short8 ah[4], al[4], bh[4], bl[4];
#pragma unroll
        for (int t = 0; t < 4; ++t) {
            ah[t] = *(const short8*)&xh[raddrA + t * 16 * LDST + ko];
            al[t] = *(const short8*)&xl[raddrA + t * 16 * LDST + ko];
            bh[t] = *(const short8*)&eh[raddrB + t * 16 * LDST + ko];
            bl[t] = *(const short8*)&el[raddrB + t * 16 * LDST + ko];
        }
#pragma unroll
        for (int mt = 0; mt < 4; ++mt)
#pragma unroll
            for (int nt = 0; nt < 4; ++nt) {
                acc[mt][nt] = __builtin_amdgcn_mfma_f32_16x16x32_bf16(ah[mt], bh[nt], acc[mt][nt], 0, 0, 0);
                acc[mt][nt] = __builtin_amdgcn_mfma_f32_16x16x32_bf16(ah[mt], bl[nt], acc[mt][nt], 0, 0, 0);
                acc[mt][nt] = __builtin_amdgcn_mfma_f32_16x16x32_bf16(al[mt], bh[nt], acc[mt][nt], 0, 0, 0);
            }
    }

    // epilogue: approx dist -> per-(row, cbk, wn) top-2 u32 keys (race-free slots)
    float xv[4][4], ev[4];
#pragma unroll
    for (int mt = 0; mt < 4; ++mt)
#pragma unroll
        for (int r = 0; r < 4; ++r)
            xv[mt][r] = xx[r0 + wm * 64 + mt * 16 + lq * 4 + r];
#pragma unroll
    for (int nt = 0; nt < 4; ++nt) ev[nt] = en[c0 + wn * 64 + nt * 16 + l15];

#pragma unroll
    for (int mt = 0; mt < 4; ++mt) {
#pragma unroll
        for (int r = 0; r < 4; ++r) {
            unsigned int b0 = 0xFFFFFFFFu, b1 = 0xFFFFFFFFu;
#pragma unroll
            for (int nt = 0; nt < 4; ++nt) {
                float dist = (xv[mt][r] + ev[nt]) - 2.0f * acc[mt][nt][r];
                unsigned int u = __float_as_uint(dist);
                u ^= (u & 0x80000000u) ? 0xFFFFFFFFu : 0x80000000u;   // order-preserving
                unsigned int key = (u & 0xFFFFF000u) |
                                   (unsigned)(c0 + wn * 64 + nt * 16 + l15);  // 12-bit idx
                if (key < b0) { b1 = b0; b0 = key; }
                else if (key < b1) b1 = key;
            }
#pragma unroll
            for (int m = 8; m; m >>= 1) {   // top-2 merge across the 16-lane col group
                unsigned int o0 = __shfl_xor(b0, m, 64);
                unsigned int o1 = __shfl_xor(b1, m, 64);
                unsigned int hi = b0 > o0 ? b0 : o0;
                b0 = b0 < o0 ? b0 : o0;
                unsigned int lo1 = b1 < o1 ? b1 : o1;
                b1 = hi < lo1 ? hi : lo1;
            }
            if (l15 == 0) {
                int row = r0 + wm * 64 + mt * 16 + lq * 4 + r;
                top2[(size_t)row * 64 + cbk * 2 + wn] =
                    ((unsigned long long)b0 << 32) | b1;
            }
        }
    }
}

// ------- merge: global top-4 of 128 candidates, exact f64 rescore, output -------
__global__ __launch_bounds__(256) void vq_merge(const float* __restrict__ x,
                                                const float* __restrict__ e,
                                                const float* __restrict__ en,
                                                const float* __restrict__ xx,
                                                const unsigned long long* __restrict__ top2,
                                                float* __restrict__ out,
                                                double* __restrict__ loss_acc) {
    int tid  = threadIdx.x;
    int lane = tid & 63;
    int wave = tid >> 6;
    int row  = blockIdx.x * 4 + wave;

    unsigned long long c = top2[(size_t)row * 64 + lane];
    unsigned int k0 = (unsigned int)(c >> 32);
    unsigned int k1 = (unsigned int)c;           // k0 <= k1 by construction
    unsigned int k2 = 0xFFFFFFFFu, k3 = 0xFFFFFFFFu;
#pragma unroll
    for (int m = 1; m <= 32; m <<= 1) {          // sorted-4 butterfly merge
        unsigned int o0 = __shfl_xor(k0, m, 64);
        unsigned int o1 = __shfl_xor(k1, m, 64);
        unsigned int o2 = __shfl_xor(k2, m, 64);
        unsigned int o3 = __shfl_xor(k3, m, 64);
        unsigned int t0 = min(k0, o0), s0 = max(k0, o0);
        unsigned int t1 = min(k1, o1), s1 = max(k1, o1);
        unsigned int t2 = min(k2, o2);
        unsigned int t3 = min(k3, o3);
        k0 = t0;
        k1 = min(s0, t1);
        unsigned int u = max(s0, t1);
        k2 = min(u, t2);
        k3 = min(max(u, t2), min(s1, t3));
    }
    int i0 = k0 & 0xFFF, i1 = k1 & 0xFFF, i2 = k2 & 0xFFF, i3 = k3 & 0xFFF;

    // exact rescore of 4 candidates in double
    float4 xv = reinterpret_cast<const float4*>(x)[(size_t)row * 64 + lane];
    float4 e0 = reinterpret_cast<const float4*>(e)[(size_t)i0 * 64 + lane];
    float4 e1 = reinterpret_cast<const float4*>(e)[(size_t)i1 * 64 + lane];
    float4 e2 = reinterpret_cast<const float4*>(e)[(size_t)i2 * 64 + lane];
    float4 e3 = reinterpret_cast<const float4*>(e)[(size_t)i3 * 64 + lane];
    double p0 = (double)xv.x * e0.x + (double)xv.y * e0.y + (double)xv.z * e0.z + (double)xv.w * e0.w;
    double p1 = (double)xv.x * e1.x + (double)xv.y * e1.y + (double)xv.z * e1.z + (double)xv.w * e1.w;
    double p2 = (double)xv.x * e2.x + (double)xv.y * e2.y + (double)xv.z * e2.z + (double)xv.w * e2.w;
    double p3 = (double)xv.x * e3.x + (double)xv.y * e3.y + (double)xv.z * e3.z + (double)xv.w * e3.w;
#pragma unroll
    for (int m = 32; m; m >>= 1) {
        p0 += __shfl_xor(p0, m, 64);
        p1 += __shfl_xor(p1, m, 64);
        p2 += __shfl_xor(p2, m, 64);
        p3 += __shfl_xor(p3, m, 64);
    }
    double xr = (double)xx[row];
    double d0 = (xr + (double)en[i0]) - 2.0 * p0;
    double d1 = (xr + (double)en[i1]) - 2.0 * p1;
    double d2 = (xr + (double)en[i2]) - 2.0 * p2;
    double d3 = (xr + (double)en[i3]) - 2.0 * p3;

    double bd = d0; int bi = i0; float4 v = e0;
    if (d1 < bd || (d1 == bd && i1 < bi)) { bd = d1; bi = i1; v = e1; }
    if (d2 < bd || (d2 == bd && i2 < bi)) { bd = d2; bi = i2; v = e2; }
    if (d3 < bd || (d3 == bd && i3 < bi)) { bd = d3; bi = i3; v = e3; }

    float4 o;
    o.x = xv.x + (v.x - xv.x);
    o.y = xv.y + (v.y - xv.y);
    o.z = xv.z + (v.z - xv.z);
    o.w = xv.w + (v.w - xv.w);
    reinterpret_cast<float4*>(out)[(size_t)row * 64 + lane] = o;
    if (lane == 0) out[(size_t)N_ROWS * D_DIM + row] = (float)bi;

    float sx = xv.x - v.x, sy = xv.y - v.y, sz = xv.z - v.z, sw = xv.w - v.w;
    float ls = sx * sx + sy * sy + sz * sz + sw * sw;
#pragma unroll
    for (int m = 32; m; m >>= 1) ls += __shfl_xor(ls, m, 64);
    __shared__ float lred[4];
    if (lane == 0) lred[wave] = ls;
    __syncthreads();
    if (tid == 0) {
        double tot = (double)lred[0] + (double)lred[1] + (double)lred[2] + (double)lred[3];
        atomicAdd(loss_acc, tot);
    }
}

__global__ void vq_final(const double* __restrict__ loss_acc, float* __restrict__ out) {
    float L = (float)(*loss_acc / (double)((size_t)N_ROWS * D_DIM));
    out[(size_t)N_ROWS * D_DIM + N_ROWS] = L + 0.2f * L;   // loss1 + BETA*loss2
}

extern "C" void kernel_launch(void* const* d_in, const int* in_sizes, int n_in,
                              void* d_out, int out_size, void* d_ws, size_t ws_size,
                              hipStream_t stream) {
    const float* x = (const float*)d_in[0];
    const float* e = (const float*)d_in[1];
    float* out = (float*)d_out;
    char* ws = (char*)d_ws;
    // ws: 0 loss(8B) | 64 en 16KB | 16448 xx 64KB | 81984 top2 8MB (~8.5MB total)
    double* loss_acc = (double*)ws;
    float* en = (float*)(ws + 64);
    float* xx = (float*)(ws + 64 + K_CODES * 4);
    unsigned long long* top2 = (unsigned long long*)(ws + 81984);

    vq_prep<<<5120, 256, 0, stream>>>(x, e, en, xx, loss_acc);
    vq_argmin<<<4096, 256, 0, stream>>>(x, e, en, xx, top2);
    vq_merge<<<4096, 256, 0, stream>>>(x, e, en, xx, top2, out, loss_acc);
    vq_final<<<1, 1, 0, stream>>>(loss_acc, out);
}

// Round 5
// 264.842 us; speedup vs baseline: 1.9899x; 1.1397x over previous
//
#include <hip/hip_runtime.h>
#include <hip/hip_bf16.h>

#define N_ROWS 16384   // B*T
#define K_CODES 4096
#define D_DIM 256

typedef short short8 __attribute__((ext_vector_type(8)));
typedef float floatx4 __attribute__((ext_vector_type(4)));

// async 16B global->LDS (dest = wave-uniform base + lane*16)
__device__ inline void gload_lds16(const void* g, void* l) {
    __builtin_amdgcn_global_load_lds(
        (const __attribute__((address_space(1))) void*)g,
        (__attribute__((address_space(3))) void*)l, 16, 0, 0);
}

// ---------------- prep: ||e||^2, ||x||^2, loss zero ----------------
__global__ __launch_bounds__(256) void vq_prep(const float* __restrict__ x,
                                               const float* __restrict__ e,
                                               float* __restrict__ en,
                                               float* __restrict__ xx,
                                               double* __restrict__ loss_acc) {
    int tid  = threadIdx.x;
    int w    = blockIdx.x * 4 + (tid >> 6);   // 20480 waves
    int lane = tid & 63;
    const float* src;
    float* dst;
    if (w < K_CODES) { src = e + (size_t)w * D_DIM;             dst = en + w; }
    else             { src = x + (size_t)(w - K_CODES) * D_DIM; dst = xx + (w - K_CODES); }
    float4 v = reinterpret_cast<const float4*>(src)[lane];
    float s = v.x * v.x + v.y * v.y + v.z * v.z + v.w * v.w;
#pragma unroll
    for (int m = 32; m; m >>= 1) s += __shfl_xor(s, m, 64);
    if (lane == 0) *dst = s;
    if (blockIdx.x == 0 && tid == 0) *loss_acc = 0.0;
}

// ------- pack x,e -> bf16 hi/lo global images in LDS-image order -------
// X: [rb 128][ch 8][part 2][r 128][ps 4] 16B units; content at (r,ps) holds
// dims d = ch*32 + (ps ^ (r&3))*8 .. +7  (bank swizzle baked in).
// part 0 = hi (trunc bf16), part 1 = lo (trunc of x - hi).  E: same, [cbk 32].
__global__ __launch_bounds__(256) void vq_pack(const float* __restrict__ x,
                                               const float* __restrict__ e,
                                               uint4* __restrict__ X,
                                               uint4* __restrict__ E) {
    int idx = blockIdx.x * 256 + threadIdx.x;   // 1.25M threads
    const float* src;
    uint4* dst;
    int row, part, d0;
    if (idx < (1 << 20)) {
        int ps = idx & 3, r = (idx >> 2) & 127, pt = (idx >> 9) & 1,
            ch = (idx >> 10) & 7, rb = idx >> 13;
        row = rb * 128 + r; part = pt;
        d0  = ch * 32 + (ps ^ (r & 3)) * 8;
        src = x; dst = X + idx;
    } else {
        int j = idx - (1 << 20);
        int ps = j & 3, r = (j >> 2) & 127, pt = (j >> 9) & 1,
            ch = (j >> 10) & 7, cbk = j >> 13;
        row = cbk * 128 + r; part = pt;
        d0  = ch * 32 + (ps ^ (r & 3)) * 8;
        src = e; dst = E + j;
    }
    float4 v0 = *reinterpret_cast<const float4*>(&src[(size_t)row * D_DIM + d0]);
    float4 v1 = *reinterpret_cast<const float4*>(&src[(size_t)row * D_DIM + d0 + 4]);
    float f[8] = {v0.x, v0.y, v0.z, v0.w, v1.x, v1.y, v1.z, v1.w};
    unsigned int b[8];
#pragma unroll
    for (int i = 0; i < 8; ++i) {
        unsigned int u = __float_as_uint(f[i]);
        if (part == 0) b[i] = u >> 16;                       // hi = trunc bf16
        else {
            float lo = f[i] - __uint_as_float(u & 0xFFFF0000u);  // exact residual
            b[i] = __float_as_uint(lo) >> 16;
        }
    }
    *dst = make_uint4(b[0] | (b[1] << 16), b[2] | (b[3] << 16),
                      b[4] | (b[5] << 16), b[6] | (b[7] << 16));
}

// ------- main: DMA-staged bf16 split MFMA GEMM + per-(row,cbk,wn) top-2 -------
__global__ __launch_bounds__(256) void vq_argmin(const uint4* __restrict__ X,
                                                 const uint4* __restrict__ E,
                                                 const float* __restrict__ en,
                                                 const float* __restrict__ xx,
                                                 unsigned long long* __restrict__ top2) {
    // LDS: 2048 units of 16B = 32 KB: xh[512] | xl[512] | eh[512] | el[512]
    __shared__ __align__(16) unsigned short sm[2048 * 8];

    int tid  = threadIdx.x;
    int cbk  = blockIdx.x & 31;
    int rb   = blockIdx.x >> 5;
    int r0   = rb * 128, c0 = cbk * 128;
    int lane = tid & 63;
    int wave = tid >> 6;
    int wm   = wave >> 1, wn = wave & 1;   // 2x2 wave grid, 64x64 per wave
    int l15  = lane & 15, lq = lane >> 4;

    floatx4 acc[4][4];
#pragma unroll
    for (int mt = 0; mt < 4; ++mt)
#pragma unroll
        for (int nt = 0; nt < 4; ++nt) acc[mt][nt] = (floatx4)0.f;

    const uint4* Ag = X + (size_t)rb  * 8192;   // 8 chunks * 1024 units
    const uint4* Bg = E + (size_t)cbk * 8192;

    const short8* Av = reinterpret_cast<const short8*>(sm);
    int sw = lq ^ (l15 & 3);
    int ua = (wm * 64 + l15) * 4 + sw;   // + mt*64 units per 16-row step
    int ub = (wn * 64 + l15) * 4 + sw;

    for (int ch = 0; ch < 8; ++ch) {     // 8 chunks of K=32 (hi+lo staged together)
        __syncthreads();
#pragma unroll
        for (int i = 0; i < 4; ++i) {
            int q = i * 256 + tid;       // 0..1023
            gload_lds16(Ag + ch * 1024 + q, (char*)sm + (i * 256 + wave * 64) * 16);
            gload_lds16(Bg + ch * 1024 + q, (char*)sm + ((1024 + i * 256) + wave * 64) * 16);
        }
        __syncthreads();

        short8 ah[4], al[4];
#pragma unroll
        for (int t = 0; t < 4; ++t) {
            ah[t] = Av[ua + t * 64];
            al[t] = Av[512 + ua + t * 64];
        }
#pragma unroll
        for (int nt = 0; nt < 4; ++nt) {
            short8 bh = Av[1024 + ub + nt * 64];
            short8 bl = Av[1536 + ub + nt * 64];
#pragma unroll
            for (int mt = 0; mt < 4; ++mt) {
                acc[mt][nt] = __builtin_amdgcn_mfma_f32_16x16x32_bf16(ah[mt], bh, acc[mt][nt], 0, 0, 0);
                acc[mt][nt] = __builtin_amdgcn_mfma_f32_16x16x32_bf16(ah[mt], bl, acc[mt][nt], 0, 0, 0);
                acc[mt][nt] = __builtin_amdgcn_mfma_f32_16x16x32_bf16(al[mt], bh, acc[mt][nt], 0, 0, 0);
            }
        }
    }

    // epilogue: approx dist -> per-(row, cbk, wn) top-2 u32 keys (race-free slots)
    float xv[4][4], ev[4];
#pragma unroll
    for (int mt = 0; mt < 4; ++mt)
#pragma unroll
        for (int r = 0; r < 4; ++r)
            xv[mt][r] = xx[r0 + wm * 64 + mt * 16 + lq * 4 + r];
#pragma unroll
    for (int nt = 0; nt < 4; ++nt) ev[nt] = en[c0 + wn * 64 + nt * 16 + l15];

#pragma unroll
    for (int mt = 0; mt < 4; ++mt) {
#pragma unroll
        for (int r = 0; r < 4; ++r) {
            unsigned int b0 = 0xFFFFFFFFu, b1 = 0xFFFFFFFFu;
#pragma unroll
            for (int nt = 0; nt < 4; ++nt) {
                float dist = (xv[mt][r] + ev[nt]) - 2.0f * acc[mt][nt][r];
                unsigned int u = __float_as_uint(dist);
                u ^= (u & 0x80000000u) ? 0xFFFFFFFFu : 0x80000000u;   // order-preserving
                unsigned int key = (u & 0xFFFFF000u) |
                                   (unsigned)(c0 + wn * 64 + nt * 16 + l15);  // 12-bit idx
                if (key < b0) { b1 = b0; b0 = key; }
                else if (key < b1) b1 = key;
            }
#pragma unroll
            for (int m = 8; m; m >>= 1) {   // top-2 merge across the 16-lane col group
                unsigned int o0 = __shfl_xor(b0, m, 64);
                unsigned int o1 = __shfl_xor(b1, m, 64);
                unsigned int hi = b0 > o0 ? b0 : o0;
                b0 = b0 < o0 ? b0 : o0;
                unsigned int lo1 = b1 < o1 ? b1 : o1;
                b1 = hi < lo1 ? hi : lo1;
            }
            if (l15 == 0) {
                int row = r0 + wm * 64 + mt * 16 + lq * 4 + r;
                top2[(size_t)row * 64 + cbk * 2 + wn] =
                    ((unsigned long long)b0 << 32) | b1;
            }
        }
    }
}

// ------- merge: global top-4 of 128 candidates, exact f64 rescore, output -------
__global__ __launch_bounds__(256) void vq_merge(const float* __restrict__ x,
                                                const float* __restrict__ e,
                                                const float* __restrict__ en,
                                                const float* __restrict__ xx,
                                                const unsigned long long* __restrict__ top2,
                                                float* __restrict__ out,
                                                double* __restrict__ loss_acc) {
    int tid  = threadIdx.x;
    int lane = tid & 63;
    int wave = tid >> 6;
    int row  = blockIdx.x * 4 + wave;

    unsigned long long c = top2[(size_t)row * 64 + lane];
    unsigned int k0 = (unsigned int)(c >> 32);
    unsigned int k1 = (unsigned int)c;           // k0 <= k1 by construction
    unsigned int k2 = 0xFFFFFFFFu, k3 = 0xFFFFFFFFu;
#pragma unroll
    for (int m = 1; m <= 32; m <<= 1) {          // sorted-4 butterfly merge
        unsigned int o0 = __shfl_xor(k0, m, 64);
        unsigned int o1 = __shfl_xor(k1, m, 64);
        unsigned int o2 = __shfl_xor(k2, m, 64);
        unsigned int o3 = __shfl_xor(k3, m, 64);
        unsigned int t0 = min(k0, o0), s0 = max(k0, o0);
        unsigned int t1 = min(k1, o1), s1 = max(k1, o1);
        unsigned int t2 = min(k2, o2);
        unsigned int t3 = min(k3, o3);
        k0 = t0;
        k1 = min(s0, t1);
        unsigned int u = max(s0, t1);
        k2 = min(u, t2);
        k3 = min(max(u, t2), min(s1, t3));
    }
    int i0 = k0 & 0xFFF, i1 = k1 & 0xFFF, i2 = k2 & 0xFFF, i3 = k3 & 0xFFF;

    // exact rescore of 4 candidates in double
    float4 xv = reinterpret_cast<const float4*>(x)[(size_t)row * 64 + lane];
    float4 e0 = reinterpret_cast<const float4*>(e)[(size_t)i0 * 64 + lane];
    float4 e1 = reinterpret_cast<const float4*>(e)[(size_t)i1 * 64 + lane];
    float4 e2 = reinterpret_cast<const float4*>(e)[(size_t)i2 * 64 + lane];
    float4 e3 = reinterpret_cast<const float4*>(e)[(size_t)i3 * 64 + lane];
    double p0 = (double)xv.x * e0.x + (double)xv.y * e0.y + (double)xv.z * e0.z + (double)xv.w * e0.w;
    double p1 = (double)xv.x * e1.x + (double)xv.y * e1.y + (double)xv.z * e1.z + (double)xv.w * e1.w;
    double p2 = (double)xv.x * e2.x + (double)xv.y * e2.y + (double)xv.z * e2.z + (double)xv.w * e2.w;
    double p3 = (double)xv.x * e3.x + (double)xv.y * e3.y + (double)xv.z * e3.z + (double)xv.w * e3.w;
#pragma unroll
    for (int m = 32; m; m >>= 1) {
        p0 += __shfl_xor(p0, m, 64);
        p1 += __shfl_xor(p1, m, 64);
        p2 += __shfl_xor(p2, m, 64);
        p3 += __shfl_xor(p3, m, 64);
    }
    double xr = (double)xx[row];
    double d0 = (xr + (double)en[i0]) - 2.0 * p0;
    double d1 = (xr + (double)en[i1]) - 2.0 * p1;
    double d2 = (xr + (double)en[i2]) - 2.0 * p2;
    double d3 = (xr + (double)en[i3]) - 2.0 * p3;

    double bd = d0; int bi = i0; float4 v = e0;
    if (d1 < bd || (d1 == bd && i1 < bi)) { bd = d1; bi = i1; v = e1; }
    if (d2 < bd || (d2 == bd && i2 < bi)) { bd = d2; bi = i2; v = e2; }
    if (d3 < bd || (d3 == bd && i3 < bi)) { bd = d3; bi = i3; v = e3; }

    float4 o;
    o.x = xv.x + (v.x - xv.x);
    o.y = xv.y + (v.y - xv.y);
    o.z = xv.z + (v.z - xv.z);
    o.w = xv.w + (v.w - xv.w);
    reinterpret_cast<float4*>(out)[(size_t)row * 64 + lane] = o;
    if (lane == 0) out[(size_t)N_ROWS * D_DIM + row] = (float)bi;

    float sx = xv.x - v.x, sy = xv.y - v.y, sz = xv.z - v.z, sw = xv.w - v.w;
    float ls = sx * sx + sy * sy + sz * sz + sw * sw;
#pragma unroll
    for (int m = 32; m; m >>= 1) ls += __shfl_xor(ls, m, 64);
    __shared__ float lred[4];
    if (lane == 0) lred[wave] = ls;
    __syncthreads();
    if (tid == 0) {
        double tot = (double)lred[0] + (double)lred[1] + (double)lred[2] + (double)lred[3];
        atomicAdd(loss_acc, tot);
    }
}

__global__ void vq_final(const double* __restrict__ loss_acc, float* __restrict__ out) {
    float L = (float)(*loss_acc / (double)((size_t)N_ROWS * D_DIM));
    out[(size_t)N_ROWS * D_DIM + N_ROWS] = L + 0.2f * L;   // loss1 + BETA*loss2
}

extern "C" void kernel_launch(void* const* d_in, const int* in_sizes, int n_in,
                              void* d_out, int out_size, void* d_ws, size_t ws_size,
                              hipStream_t stream) {
    const float* x = (const float*)d_in[0];
    const float* e = (const float*)d_in[1];
    float* out = (float*)d_out;
    char* ws = (char*)d_ws;
    // ws: 0 loss(8B) | 64 en 16KB | 16448 xx 64KB | 81984 top2 8MB
    //     | 8470592 Ximg 16MB | 25247808 Eimg 4MB  (~28.2 MB total)
    double* loss_acc = (double*)ws;
    float* en = (float*)(ws + 64);
    float* xx = (float*)(ws + 64 + K_CODES * 4);
    unsigned long long* top2 = (unsigned long long*)(ws + 81984);
    uint4* Ximg = (uint4*)(ws + 8470592);
    uint4* Eimg = (uint4*)(ws + 25247808);

    vq_prep<<<5120, 256, 0, stream>>>(x, e, en, xx, loss_acc);
    vq_pack<<<5120, 256, 0, stream>>>(x, e, Ximg, Eimg);
    vq_argmin<<<4096, 256, 0, stream>>>(Ximg, Eimg, en, xx, top2);
    vq_merge<<<4096, 256, 0, stream>>>(x, e, en, xx, top2, out, loss_acc);
    vq_final<<<1, 1, 0, stream>>>(loss_acc, out);
}